// Round 16
// baseline (231.202 us; speedup 1.0000x reference)
//
#include <hip/hip_runtime.h>
#include <hip/hip_bf16.h>
#include <hip/hip_fp16.h>
#include <cmath>

static constexpr int HN = 12;      // heads
static constexpr int DHEAD = 64;   // head dim
static constexpr int DMODEL = 768;
static constexpr int NQ = 1024;    // seq len (q == k)
static constexpr int NB = 4;       // batch
static constexpr int NCH = 4;      // KV split chunks (256 keys each)
static constexpr int MROWS = NB * NQ;        // 4096
static constexpr size_t PER = (size_t)NB * HN * NQ * DHEAD;  // 3,145,728
static constexpr size_t WN  = (size_t)DMODEL * DMODEL;       // 589,824
static constexpr size_t CHROWS = (size_t)NB * HN * NQ;       // 49,152 rows/chunk
static constexpr size_t SCN = (size_t)NB * HN * NQ * NQ;     // 50,331,648 scale elems

typedef __attribute__((ext_vector_type(8))) short bf16x8;
typedef __attribute__((ext_vector_type(4))) float f32x4;

static __device__ __forceinline__ unsigned short f2bf(float f) {
    unsigned int u = __builtin_bit_cast(unsigned int, f);
    unsigned int r = (u + 0x7FFFu + ((u >> 16) & 1u)) >> 16;
    return (unsigned short)r;
}
static __device__ __forceinline__ unsigned pack2(float lo, float hi) {
    return (unsigned)f2bf(lo) | ((unsigned)f2bf(hi) << 16);
}
static __device__ __forceinline__ unsigned short f2h(float f) {
    return __half_as_ushort(__float2half(f));
}
static __device__ __forceinline__ float bf2f(unsigned short u) {
    return __builtin_bit_cast(float, (unsigned)u << 16);
}

// async global->LDS, 16B per lane; LDS dest must be wave-uniform base.
typedef const __attribute__((address_space(1))) unsigned int gu32;
typedef __attribute__((address_space(3))) unsigned int lu32;
static __device__ __forceinline__ void gload16(const void* g, void* l) {
    __builtin_amdgcn_global_load_lds((gu32*)g, (lu32*)l, 16, 0, 0);
}

// ---------- prepass: fuse aw + mask + 0.125 -> bf16 sentinel array ----------
// masked -> -1.0 (bf16 0xBF80, sign bit = sentinel); else 0.125*aw (aw>=0).
// Pure streaming: read 402 MB + write 101 MB, fully coalesced.
__global__ __launch_bounds__(256)
void fuse_scale(const float* __restrict__ aw, const int* __restrict__ mask,
                unsigned short* __restrict__ scb)
{
    const size_t stride = (size_t)gridDim.x * 256 * 8;
    size_t base = ((size_t)blockIdx.x * 256 + threadIdx.x) * 8;
    for (; base < SCN; base += stride) {
        float4 a0 = *(const float4*)&aw[base];
        float4 a1 = *(const float4*)&aw[base + 4];
        int4   m0 = *(const int4*)&mask[base];
        int4   m1 = *(const int4*)&mask[base + 4];
        ushort4 u0, u1;
        u0.x = m0.x ? (unsigned short)0xBF80u : f2bf(0.125f * a0.x);
        u0.y = m0.y ? (unsigned short)0xBF80u : f2bf(0.125f * a0.y);
        u0.z = m0.z ? (unsigned short)0xBF80u : f2bf(0.125f * a0.z);
        u0.w = m0.w ? (unsigned short)0xBF80u : f2bf(0.125f * a0.w);
        u1.x = m1.x ? (unsigned short)0xBF80u : f2bf(0.125f * a1.x);
        u1.y = m1.y ? (unsigned short)0xBF80u : f2bf(0.125f * a1.y);
        u1.z = m1.z ? (unsigned short)0xBF80u : f2bf(0.125f * a1.z);
        u1.w = m1.w ? (unsigned short)0xBF80u : f2bf(0.125f * a1.w);
        *(ushort4*)&scb[base]     = u0;
        *(ushort4*)&scb[base + 4] = u1;
    }
}

// ---------- converts ----------
__global__ __launch_bounds__(256)
void cvt3(const float* __restrict__ a, const float* __restrict__ b, const float* __restrict__ c,
          unsigned short* __restrict__ oa, unsigned short* __restrict__ ob, unsigned short* __restrict__ oc)
{
    const int z = blockIdx.z;
    const float* s = z == 0 ? a : z == 1 ? b : c;
    unsigned short* d = z == 0 ? oa : z == 1 ? ob : oc;
    size_t i = ((size_t)blockIdx.x * 256 + threadIdx.x) * 4;
    float4 v = *(const float4*)&s[i];
    ushort4 u;
    u.x = f2bf(v.x); u.y = f2bf(v.y); u.z = f2bf(v.z); u.w = f2bf(v.w);
    *(ushort4*)&d[i] = u;
}

// W[k][n] f32 -> Wt[n][k] bf16 (768x768 per tensor)
__global__ __launch_bounds__(256)
void wtrans(const float* __restrict__ w0, const float* __restrict__ w1,
            const float* __restrict__ w2, const float* __restrict__ w3,
            unsigned short* __restrict__ o0, unsigned short* __restrict__ o1,
            unsigned short* __restrict__ o2, unsigned short* __restrict__ o3)
{
    const int z = blockIdx.z;
    const float* in = z == 0 ? w0 : z == 1 ? w1 : z == 2 ? w2 : w3;
    unsigned short* out = z == 0 ? o0 : z == 1 ? o1 : z == 2 ? o2 : o3;
    __shared__ float t[64][65];
    const int tid = threadIdx.x;
    const int k0 = blockIdx.x * 64, n0 = blockIdx.y * 64;
    #pragma unroll
    for (int l = 0; l < 16; ++l) {
        int idx = l * 256 + tid, r = idx >> 6, cc = idx & 63;
        t[r][cc] = in[(size_t)(k0 + r) * DMODEL + n0 + cc];
    }
    __syncthreads();
    #pragma unroll
    for (int l = 0; l < 16; ++l) {
        int idx = l * 256 + tid, r = idx >> 6, cc = idx & 63;
        out[(size_t)(n0 + r) * DMODEL + k0 + cc] = f2bf(t[cc][r]);
    }
}

// ---------- bf16 MFMA GEMM (128x128 tile, BK=64, 4 waves, gload_lds staging) ----------
static __device__ __forceinline__
void gemm_body(const unsigned short* __restrict__ A, const unsigned short* __restrict__ Wt,
               const float* __restrict__ bias, void* __restrict__ C, int layout)
{
    constexpr int K = DMODEL;
    __shared__ unsigned short As[128 * 64];
    __shared__ unsigned short Bs[128 * 64];
    const int tid = threadIdx.x, w = tid >> 6, lane = tid & 63;
    const int c = lane & 15, g = lane >> 4;
    const int wr = w >> 1, wc = w & 1;
    const int bn = blockIdx.x * 128, bm = blockIdx.y * 128;

    f32x4 acc[4][4] = {};
    for (int k0 = 0; k0 < K; k0 += 64) {
        #pragma unroll
        for (int it = 0; it < 4; ++it) {
            int idx = it * 256 + tid, r = idx >> 3, blk = idx & 7;
            int so = (blk ^ (r & 7)) << 3;
            gload16(A  + (size_t)(bm + r) * K + k0 + so, &As[(it * 256 + w * 64) * 8]);
            gload16(Wt + (size_t)(bn + r) * K + k0 + so, &Bs[(it * 256 + w * 64) * 8]);
        }
        __syncthreads();
        #pragma unroll
        for (int kk = 0; kk < 2; ++kk) {
            bf16x8 a[4], b[4];
            #pragma unroll
            for (int mi = 0; mi < 4; ++mi) {
                int row = wr * 64 + mi * 16 + c;
                a[mi] = *(const bf16x8*)&As[row * 64 + ((((kk << 2) | g) ^ (row & 7)) << 3)];
            }
            #pragma unroll
            for (int ni = 0; ni < 4; ++ni) {
                int row = wc * 64 + ni * 16 + c;
                b[ni] = *(const bf16x8*)&Bs[row * 64 + ((((kk << 2) | g) ^ (row & 7)) << 3)];
            }
            #pragma unroll
            for (int mi = 0; mi < 4; ++mi)
                #pragma unroll
                for (int ni = 0; ni < 4; ++ni)
                    acc[mi][ni] = __builtin_amdgcn_mfma_f32_16x16x32_bf16(a[mi], b[ni], acc[mi][ni], 0, 0, 0);
        }
        __syncthreads();
    }

    #pragma unroll
    for (int ni = 0; ni < 4; ++ni) {
        int col = bn + wc * 64 + ni * 16 + c;
        float bvx = bias[col];
        int hh = col >> 6, d = col & 63;
        #pragma unroll
        for (int mi = 0; mi < 4; ++mi) {
            int m0 = bm + wr * 64 + mi * 16 + 4 * g;
            int bb = m0 >> 10, nn0 = m0 & (NQ - 1);
            if (layout == 0) {
                float* o = (float*)C;
                #pragma unroll
                for (int j = 0; j < 4; ++j)
                    o[(size_t)(m0 + j) * DMODEL + col] = acc[mi][ni][j] + bvx;
            } else if (layout == 1) {
                unsigned short* o = (unsigned short*)C;
                #pragma unroll
                for (int j = 0; j < 4; ++j)
                    o[(((size_t)bb * HN + hh) * NQ + nn0 + j) * DHEAD + d] =
                        f2bf(acc[mi][ni][j] + bvx);
            } else {
                unsigned short* o = (unsigned short*)C;
                ushort4 u;
                u.x = f2bf(acc[mi][ni][0] + bvx);
                u.y = f2bf(acc[mi][ni][1] + bvx);
                u.z = f2bf(acc[mi][ni][2] + bvx);
                u.w = f2bf(acc[mi][ni][3] + bvx);
                *(ushort4*)&o[(((size_t)bb * HN + hh) * DHEAD + d) * NQ + nn0] = u;
            }
        }
    }
}

__global__ __launch_bounds__(256)
void qkv_gemm(const unsigned short* __restrict__ qa, const unsigned short* __restrict__ ka,
              const unsigned short* __restrict__ va,
              const unsigned short* __restrict__ wq, const unsigned short* __restrict__ wk,
              const unsigned short* __restrict__ wv,
              const float* __restrict__ bq, const float* __restrict__ bk, const float* __restrict__ bv,
              unsigned short* __restrict__ qo, unsigned short* __restrict__ ko,
              unsigned short* __restrict__ vo)
{
    const int z = blockIdx.z;
    const unsigned short* A  = z == 0 ? qa : z == 1 ? ka : va;
    const unsigned short* Wt = z == 0 ? wq : z == 1 ? wk : wv;
    const float* bias        = z == 0 ? bq : z == 1 ? bk : bv;
    unsigned short* C        = z == 0 ? qo : z == 1 ? ko : vo;
    gemm_body(A, Wt, bias, C, z == 2 ? 2 : 1);
}

__global__ __launch_bounds__(256)
void o_gemm(const unsigned short* __restrict__ A, const unsigned short* __restrict__ Wt,
            const float* __restrict__ bias, float* __restrict__ C)
{
    gemm_body(A, Wt, bias, C, 0);
}

// ---------- attention, split-KV partials ----------
// R13 discipline (KVBLK=32, double-buffered, 1 __syncthreads/tile, gload16
// staging) but consuming the PREPASSED bf16 sentinel scale (101 MB stream,
// 4x fewer bytes than raw aw+mask). Per buffer: K 4K + V 4K + sc 4K = 12.5K;
// dbuf total 25.5 KB -> ~6 blocks/CU (24 waves). Scale staged with the
// granule-XOR source swizzle (linear LDS dest, rule #21); granule = 8 keys.
__global__ __launch_bounds__(256)
void attn_part(const unsigned short* __restrict__ qws,
               const unsigned short* __restrict__ kws,
               const unsigned short* __restrict__ vtws,
               const unsigned short* __restrict__ scb,
               const float* __restrict__ lm,
               unsigned short* __restrict__ opart, float* __restrict__ mpart,
               float* __restrict__ lpart)
{
    const int qt = blockIdx.x, h = blockIdx.y;
    const int b = blockIdx.z >> 2, ch = blockIdx.z & 3;
    const int tid = threadIdx.x;
    const int w = tid >> 6, lane = tid & 63;
    const int c = lane & 15, g = lane >> 4;

    __shared__ unsigned short Ks[2][32 * 64];   // 32 keys x 64 d, XOR-swizzled
    __shared__ unsigned short Vs[2][64 * 32];   // 64 d x 32 keys, XOR-swizzled
    __shared__ unsigned short scS[2][64 * 32];  // 64 q x 32 keys bf16 scale
    __shared__ float lms[256];

    const size_t bh = (size_t)b * HN + h;
    const unsigned short* qbase  = qws  + (bh * NQ + (size_t)qt * 64) * DHEAD;
    const unsigned short* kbase  = kws  + (bh * NQ + (size_t)ch * 256) * DHEAD;
    const unsigned short* vtbase = vtws + bh * DHEAD * NQ + ch * 256;
    const unsigned short* scbase = scb + (bh * NQ + (size_t)qt * 64) * NQ + ch * 256;

    // sc staging: thread t -> row q = t>>2, slot G = t&3, source granule
    // Gs = G ^ (q&3) (granule = 8 keys = 16B). Linear LDS dest = t*8 shorts.
    const int sq = tid >> 2;
    const int sGs = (tid & 3) ^ (sq & 3);

    auto stage = [&](int kt, int bufi) {
        {   // K: 32 rows x 64 d
            int r = tid >> 3, blk = tid & 7;
            gload16(kbase + (size_t)(kt * 32 + r) * DHEAD + ((blk ^ (r & 7)) << 3),
                    &Ks[bufi][w * 512]);
        }
        {   // V: 64 d x 32 keys
            int rv = tid >> 2, blkv = tid & 3;
            gload16(vtbase + (size_t)rv * NQ + kt * 32 + ((blkv ^ ((tid >> 4) & 3)) << 3),
                    &Vs[bufi][w * 512]);
        }
        {   // sc: 64 q x 32 keys bf16
            gload16(scbase + (size_t)sq * NQ + kt * 32 + sGs * 8, &scS[bufi][w * 512]);
        }
    };

    // Q fragments (q-row = w*16 + c) direct from global
    const int qrow = w * 16 + c;
    const bf16x8 qf0 = *(const bf16x8*)&qbase[qrow * DHEAD + g * 8];
    const bf16x8 qf1 = *(const bf16x8*)&qbase[qrow * DHEAD + 32 + g * 8];

    f32x4 O[4] = {{0,0,0,0},{0,0,0,0},{0,0,0,0},{0,0,0,0}};
    float mrun = -1e30f, lrun = 0.f;
    const int srcl = c + ((g & 1) << 5);   // c + 32*(g&1)
    const bool hiT = (g >> 1) != 0;
    const int vsw = (c >> 2);              // V read swizzle
    // sc read: lane needs keys nt*16+4g..+3 -> granule Gr = nt*2+(g>>1),
    // slot = Gr ^ (qrow&3), element offset (g&1)*4.
    const int rpA = qrow * 32 + (((g >> 1) ^ (qrow & 3)) << 3) + ((g & 1) << 2);
    const int rpB = qrow * 32 + (((2 + (g >> 1)) ^ (qrow & 3)) << 3) + ((g & 1) << 2);

    lms[tid] = lm[((size_t)b * NQ + ch * 256 + tid) * HN + h];
    stage(0, 0);
    __syncthreads();   // lms written + tile 0 staged

    #pragma unroll
    for (int kt = 0; kt < 8; ++kt) {
        const int cur = kt & 1;
        if (kt < 7) stage(kt + 1, cur ^ 1);

        // scale + lm from LDS (staged one tile ago)
        ushort4 sc4[2]; float4 lm4[2];
        sc4[0] = *(const ushort4*)&scS[cur][rpA];
        sc4[1] = *(const ushort4*)&scS[cur][rpB];
        lm4[0] = *(const float4*)&lms[kt * 32 + 4 * g];
        lm4[1] = *(const float4*)&lms[kt * 32 + 16 + 4 * g];

        // S^T = K Q^T  (rows=keys 32, cols=q 16)
        f32x4 s[2] = {{0,0,0,0},{0,0,0,0}};
        #pragma unroll
        for (int kk = 0; kk < 2; ++kk) {
            bf16x8 qf = kk ? qf1 : qf0;
            #pragma unroll
            for (int nt = 0; nt < 2; ++nt) {
                int krow = nt * 16 + c;
                bf16x8 kf = *(const bf16x8*)&Ks[cur][krow * 64 + ((((kk << 2) | g) ^ (c & 7)) << 3)];
                s[nt] = __builtin_amdgcn_mfma_f32_16x16x32_bf16(kf, qf, s[nt], 0, 0, 0);
            }
        }

        // scores + online softmax (per lane: one q=c, 8 keys)
        float p[2][4];
        float tmax = -INFINITY;
        #pragma unroll
        for (int nt = 0; nt < 2; ++nt) {
            const unsigned short* su = (const unsigned short*)&sc4[nt];
            const float* lv = (const float*)&lm4[nt];
            #pragma unroll
            for (int j = 0; j < 4; ++j) {
                unsigned short u = su[j];
                float v = (u & 0x8000u) ? -1e30f : fmaf(s[nt][j], bf2f(u), lv[j]);
                p[nt][j] = v;
                tmax = fmaxf(tmax, v);
            }
        }
        tmax = fmaxf(tmax, __shfl_xor(tmax, 16));
        tmax = fmaxf(tmax, __shfl_xor(tmax, 32));

        float mn = fmaxf(mrun, tmax);
        float scal = __expf(mrun - mn);
        mrun = mn;
        float rs = 0.f;
        #pragma unroll
        for (int nt = 0; nt < 2; ++nt)
            #pragma unroll
            for (int j = 0; j < 4; ++j) {
                float e = __expf(p[nt][j] - mn);
                p[nt][j] = e;
                rs += e;
            }
        rs += __shfl_xor(rs, 16);
        rs += __shfl_xor(rs, 32);
        lrun = lrun * scal + rs;
        #pragma unroll
        for (int nd = 0; nd < 4; ++nd) O[nd] *= scal;

        // pack P to bf16 pairs
        int pk[2][2];
        #pragma unroll
        for (int nt = 0; nt < 2; ++nt) {
            pk[nt][0] = (int)pack2(p[nt][0], p[nt][1]);
            pk[nt][1] = (int)pack2(p[nt][2], p[nt][3]);
        }

        // PV: O^T += V^T P^T ; B-frag (keys 8g..8g+7, q=c) via shfl
        {
            int xa0 = __shfl(pk[0][0], srcl),      xb0 = __shfl(pk[1][0], srcl);
            int xa1 = __shfl(pk[0][1], srcl),      xb1 = __shfl(pk[1][1], srcl);
            int xa2 = __shfl(pk[0][0], srcl + 16), xb2 = __shfl(pk[1][0], srcl + 16);
            int xa3 = __shfl(pk[0][1], srcl + 16), xb3 = __shfl(pk[1][1], srcl + 16);
            int4 bi;
            bi.x = hiT ? xb0 : xa0;
            bi.y = hiT ? xb1 : xa1;
            bi.z = hiT ? xb2 : xa2;
            bi.w = hiT ? xb3 : xa3;
            bf16x8 pa = __builtin_bit_cast(bf16x8, bi);
            #pragma unroll
            for (int nd = 0; nd < 4; ++nd) {
                int vrow = nd * 16 + c;
                bf16x8 vf = *(const bf16x8*)&Vs[cur][vrow * 32 + ((g ^ vsw) << 3)];
                O[nd] = __builtin_amdgcn_mfma_f32_16x16x32_bf16(vf, pa, O[nd], 0, 0, 0);
            }
        }
        if (kt < 7) __syncthreads();   // reads of cur done; staged tile visible
    }

    // store un-normalized partials as fp16 (d = nd*16 + 4g + j)
    const size_t prow = ((size_t)(ch * NB + b) * HN + h) * NQ + qt * 64 + qrow;
    #pragma unroll
    for (int nd = 0; nd < 4; ++nd) {
        ushort4 u;
        u.x = f2h(O[nd][0]); u.y = f2h(O[nd][1]);
        u.z = f2h(O[nd][2]); u.w = f2h(O[nd][3]);
        *(ushort4*)&opart[prow * 64 + nd * 16 + 4 * g] = u;
    }
    if (g == 0) {
        mpart[prow] = mrun;
        lpart[prow] = lrun;
    }
}

// ---------- combine partials ----------
__global__ __launch_bounds__(256)
void attn_combine(const unsigned short* __restrict__ opart, const float* __restrict__ mpart,
                  const float* __restrict__ lpart, unsigned short* __restrict__ out)
{
    const int qt = blockIdx.x, h = blockIdx.y, b = blockIdx.z;
    const int tid = threadIdx.x;
    const int q = qt * 64 + (tid >> 2);
    const int d0 = (tid & 3) * 16;
    const size_t row = ((size_t)b * HN + h) * NQ + q;

    float mv[NCH], lv[NCH];
    float M = -INFINITY;
    #pragma unroll
    for (int ci = 0; ci < NCH; ++ci) {
        mv[ci] = mpart[ci * CHROWS + row];
        lv[ci] = lpart[ci * CHROWS + row];
        M = fmaxf(M, mv[ci]);
    }
    float L = 0.f;
    float wc[NCH];
    #pragma unroll
    for (int ci = 0; ci < NCH; ++ci) {
        wc[ci] = __expf(mv[ci] - M);
        L += lv[ci] * wc[ci];
    }
    const float inv = 1.f / L;

    float o[16] = {};
    #pragma unroll
    for (int ci = 0; ci < NCH; ++ci) {
        const unsigned short* src = opart + (ci * CHROWS + row) * 64 + d0;
        #pragma unroll
        for (int i = 0; i < 4; ++i) {
            ushort4 u = *(const ushort4*)&src[i * 4];
            o[i * 4 + 0] += wc[ci] * __half2float(__ushort_as_half(u.x));
            o[i * 4 + 1] += wc[ci] * __half2float(__ushort_as_half(u.y));
            o[i * 4 + 2] += wc[ci] * __half2float(__ushort_as_half(u.z));
            o[i * 4 + 3] += wc[ci] * __half2float(__ushort_as_half(u.w));
        }
    }
    const size_t ob = ((size_t)b * NQ + q) * DMODEL + h * DHEAD + d0;
    #pragma unroll
    for (int i = 0; i < 4; ++i) {
        ushort4 u;
        u.x = f2bf(o[i * 4 + 0] * inv);
        u.y = f2bf(o[i * 4 + 1] * inv);
        u.z = f2bf(o[i * 4 + 2] * inv);
        u.w = f2bf(o[i * 4 + 3] * inv);
        *(ushort4*)&out[ob + i * 4] = u;
    }
}

extern "C" void kernel_launch(void* const* d_in, const int* in_sizes, int n_in,
                              void* d_out, int out_size, void* d_ws, size_t ws_size,
                              hipStream_t stream)
{
    const float* queries = (const float*)d_in[0];
    const float* keys    = (const float*)d_in[1];
    const float* values  = (const float*)d_in[2];
    const float* lossmap = (const float*)d_in[3];
    const int*   mask    = (const int*)d_in[4];
    const float* aw      = (const float*)d_in[5];
    const float* Wq = (const float*)d_in[6];
    const float* bq = (const float*)d_in[7];
    const float* Wk = (const float*)d_in[8];
    const float* bk = (const float*)d_in[9];
    const float* Wv = (const float*)d_in[10];
    const float* bv = (const float*)d_in[11];
    const float* Wo = (const float*)d_in[12];
    const float* bo = (const float*)d_in[13];

    unsigned short* p = (unsigned short*)d_ws;
    unsigned short* qbf  = p; p += PER;
    unsigned short* kbf  = p; p += PER;
    unsigned short* vbf  = p; p += PER;
    unsigned short* qws  = p; p += PER;
    unsigned short* kws  = p; p += PER;
    unsigned short* vtws = p; p += PER;
    unsigned short* aobf = p; p += PER;
    unsigned short* wqt  = p; p += WN;
    unsigned short* wkt  = p; p += WN;
    unsigned short* wvt  = p; p += WN;
    unsigned short* wot  = p; p += WN;
    unsigned short* opart = p; p += (size_t)NCH * CHROWS * 64;   // 25.2 MB fp16
    unsigned short* scb   = p; p += SCN;                          // 100.7 MB bf16
    float* fp = (float*)p;
    float* mpart = fp; fp += (size_t)NCH * CHROWS;
    float* lpart = fp; fp += (size_t)NCH * CHROWS;

    const int M = MROWS;  // 4096
    fuse_scale<<<dim3(6144), 256, 0, stream>>>(aw, mask, scb);
    cvt3<<<dim3((unsigned)(PER / 1024), 1, 3), 256, 0, stream>>>(queries, keys, values, qbf, kbf, vbf);
    wtrans<<<dim3(12, 12, 4), 256, 0, stream>>>(Wq, Wk, Wv, Wo, wqt, wkt, wvt, wot);
    qkv_gemm<<<dim3(DMODEL / 128, M / 128, 3), 256, 0, stream>>>(
        qbf, kbf, vbf, wqt, wkt, wvt, bq, bk, bv, qws, kws, vtws);
    attn_part<<<dim3(NQ / 64, HN, NB * NCH), 256, 0, stream>>>(
        qws, kws, vtws, scb, lossmap, opart, mpart, lpart);
    attn_combine<<<dim3(NQ / 64, HN, NB), 256, 0, stream>>>(opart, mpart, lpart, aobf);
    o_gemm<<<dim3(DMODEL / 128, M / 128), 256, 0, stream>>>(aobf, wot, bo, (float*)d_out);
}

// Round 17
// 183.256 us; speedup vs baseline: 1.2616x; 1.2616x over previous
//
#include <hip/hip_runtime.h>
#include <hip/hip_bf16.h>
#include <hip/hip_fp16.h>
#include <cmath>

static constexpr int HN = 12;      // heads
static constexpr int DHEAD = 64;   // head dim
static constexpr int DMODEL = 768;
static constexpr int NQ = 1024;    // seq len (q == k)
static constexpr int NB = 4;       // batch
static constexpr int NCH = 4;      // KV split chunks
static constexpr int MROWS = NB * NQ;        // 4096
static constexpr size_t PER = (size_t)NB * HN * NQ * DHEAD;  // 3,145,728
static constexpr size_t WN  = (size_t)DMODEL * DMODEL;       // 589,824
static constexpr size_t CHROWS = (size_t)NB * HN * NQ;       // 49,152 rows/chunk

typedef __attribute__((ext_vector_type(8))) short bf16x8;
typedef __attribute__((ext_vector_type(4))) float f32x4;

static __device__ __forceinline__ unsigned short f2bf(float f) {
    unsigned int u = __builtin_bit_cast(unsigned int, f);
    unsigned int r = (u + 0x7FFFu + ((u >> 16) & 1u)) >> 16;
    return (unsigned short)r;
}
static __device__ __forceinline__ unsigned pack2(float lo, float hi) {
    return (unsigned)f2bf(lo) | ((unsigned)f2bf(hi) << 16);
}
static __device__ __forceinline__ unsigned short f2h(float f) {
    return __half_as_ushort(__float2half(f));
}

// async global->LDS, 16B per lane; LDS dest must be wave-uniform base.
typedef const __attribute__((address_space(1))) unsigned int gu32;
typedef __attribute__((address_space(3))) unsigned int lu32;
static __device__ __forceinline__ void gload16(const void* g, void* l) {
    __builtin_amdgcn_global_load_lds((gu32*)g, (lu32*)l, 16, 0, 0);
}

// ---------- converts ----------
__global__ __launch_bounds__(256)
void cvt3(const float* __restrict__ a, const float* __restrict__ b, const float* __restrict__ c,
          unsigned short* __restrict__ oa, unsigned short* __restrict__ ob, unsigned short* __restrict__ oc)
{
    const int z = blockIdx.z;
    const float* s = z == 0 ? a : z == 1 ? b : c;
    unsigned short* d = z == 0 ? oa : z == 1 ? ob : oc;
    size_t i = ((size_t)blockIdx.x * 256 + threadIdx.x) * 4;
    float4 v = *(const float4*)&s[i];
    ushort4 u;
    u.x = f2bf(v.x); u.y = f2bf(v.y); u.z = f2bf(v.z); u.w = f2bf(v.w);
    *(ushort4*)&d[i] = u;
}

// W[k][n] f32 -> Wt[n][k] bf16 (768x768 per tensor)
__global__ __launch_bounds__(256)
void wtrans(const float* __restrict__ w0, const float* __restrict__ w1,
            const float* __restrict__ w2, const float* __restrict__ w3,
            unsigned short* __restrict__ o0, unsigned short* __restrict__ o1,
            unsigned short* __restrict__ o2, unsigned short* __restrict__ o3)
{
    const int z = blockIdx.z;
    const float* in = z == 0 ? w0 : z == 1 ? w1 : z == 2 ? w2 : w3;
    unsigned short* out = z == 0 ? o0 : z == 1 ? o1 : z == 2 ? o2 : o3;
    __shared__ float t[64][65];
    const int tid = threadIdx.x;
    const int k0 = blockIdx.x * 64, n0 = blockIdx.y * 64;
    #pragma unroll
    for (int l = 0; l < 16; ++l) {
        int idx = l * 256 + tid, r = idx >> 6, cc = idx & 63;
        t[r][cc] = in[(size_t)(k0 + r) * DMODEL + n0 + cc];
    }
    __syncthreads();
    #pragma unroll
    for (int l = 0; l < 16; ++l) {
        int idx = l * 256 + tid, r = idx >> 6, cc = idx & 63;
        out[(size_t)(n0 + r) * DMODEL + k0 + cc] = f2bf(t[cc][r]);
    }
}

// ---------- bf16 MFMA GEMM (128x128 tile, BK=64, 4 waves, gload_lds staging) ----------
static __device__ __forceinline__
void gemm_body(const unsigned short* __restrict__ A, const unsigned short* __restrict__ Wt,
               const float* __restrict__ bias, void* __restrict__ C, int layout)
{
    constexpr int K = DMODEL;
    __shared__ unsigned short As[128 * 64];
    __shared__ unsigned short Bs[128 * 64];
    const int tid = threadIdx.x, w = tid >> 6, lane = tid & 63;
    const int c = lane & 15, g = lane >> 4;
    const int wr = w >> 1, wc = w & 1;
    const int bn = blockIdx.x * 128, bm = blockIdx.y * 128;

    f32x4 acc[4][4] = {};
    for (int k0 = 0; k0 < K; k0 += 64) {
        #pragma unroll
        for (int it = 0; it < 4; ++it) {
            int idx = it * 256 + tid, r = idx >> 3, blk = idx & 7;
            int so = (blk ^ (r & 7)) << 3;
            gload16(A  + (size_t)(bm + r) * K + k0 + so, &As[(it * 256 + w * 64) * 8]);
            gload16(Wt + (size_t)(bn + r) * K + k0 + so, &Bs[(it * 256 + w * 64) * 8]);
        }
        __syncthreads();
        #pragma unroll
        for (int kk = 0; kk < 2; ++kk) {
            bf16x8 a[4], b[4];
            #pragma unroll
            for (int mi = 0; mi < 4; ++mi) {
                int row = wr * 64 + mi * 16 + c;
                a[mi] = *(const bf16x8*)&As[row * 64 + ((((kk << 2) | g) ^ (row & 7)) << 3)];
            }
            #pragma unroll
            for (int ni = 0; ni < 4; ++ni) {
                int row = wc * 64 + ni * 16 + c;
                b[ni] = *(const bf16x8*)&Bs[row * 64 + ((((kk << 2) | g) ^ (row & 7)) << 3)];
            }
            #pragma unroll
            for (int mi = 0; mi < 4; ++mi)
                #pragma unroll
                for (int ni = 0; ni < 4; ++ni)
                    acc[mi][ni] = __builtin_amdgcn_mfma_f32_16x16x32_bf16(a[mi], b[ni], acc[mi][ni], 0, 0, 0);
        }
        __syncthreads();
    }

    #pragma unroll
    for (int ni = 0; ni < 4; ++ni) {
        int col = bn + wc * 64 + ni * 16 + c;
        float bvx = bias[col];
        int hh = col >> 6, d = col & 63;
        #pragma unroll
        for (int mi = 0; mi < 4; ++mi) {
            int m0 = bm + wr * 64 + mi * 16 + 4 * g;
            int bb = m0 >> 10, nn0 = m0 & (NQ - 1);
            if (layout == 0) {
                float* o = (float*)C;
                #pragma unroll
                for (int j = 0; j < 4; ++j)
                    o[(size_t)(m0 + j) * DMODEL + col] = acc[mi][ni][j] + bvx;
            } else if (layout == 1) {
                unsigned short* o = (unsigned short*)C;
                #pragma unroll
                for (int j = 0; j < 4; ++j)
                    o[(((size_t)bb * HN + hh) * NQ + nn0 + j) * DHEAD + d] =
                        f2bf(acc[mi][ni][j] + bvx);
            } else {
                unsigned short* o = (unsigned short*)C;
                ushort4 u;
                u.x = f2bf(acc[mi][ni][0] + bvx);
                u.y = f2bf(acc[mi][ni][1] + bvx);
                u.z = f2bf(acc[mi][ni][2] + bvx);
                u.w = f2bf(acc[mi][ni][3] + bvx);
                *(ushort4*)&o[(((size_t)bb * HN + hh) * DHEAD + d) * NQ + nn0] = u;
            }
        }
    }
}

__global__ __launch_bounds__(256)
void qkv_gemm(const unsigned short* __restrict__ qa, const unsigned short* __restrict__ ka,
              const unsigned short* __restrict__ va,
              const unsigned short* __restrict__ wq, const unsigned short* __restrict__ wk,
              const unsigned short* __restrict__ wv,
              const float* __restrict__ bq, const float* __restrict__ bk, const float* __restrict__ bv,
              unsigned short* __restrict__ qo, unsigned short* __restrict__ ko,
              unsigned short* __restrict__ vo)
{
    const int z = blockIdx.z;
    const unsigned short* A  = z == 0 ? qa : z == 1 ? ka : va;
    const unsigned short* Wt = z == 0 ? wq : z == 1 ? wk : wv;
    const float* bias        = z == 0 ? bq : z == 1 ? bk : bv;
    unsigned short* C        = z == 0 ? qo : z == 1 ? ko : vo;
    gemm_body(A, Wt, bias, C, z == 2 ? 2 : 1);
}

__global__ __launch_bounds__(256)
void o_gemm(const unsigned short* __restrict__ A, const unsigned short* __restrict__ Wt,
            const float* __restrict__ bias, float* __restrict__ C)
{
    gemm_body(A, Wt, bias, C, 0);
}

// ---------- attention, split-KV partials ----------
// R13 (best verified): KVBLK=32, double-buffered, 1 barrier/tile; aw and
// mask staged via global_load_lds (fire-and-forget, consumed one tile later).
// Validated at the platform's practical streaming rate for this mix
// (~2.8 TB/s read; the R16 pure-streamer control hit 3.0).
__global__ __launch_bounds__(256, 3)
void attn_part(const unsigned short* __restrict__ qws,
               const unsigned short* __restrict__ kws,
               const unsigned short* __restrict__ vtws,
               const float* __restrict__ aw, const int* __restrict__ mask,
               const float* __restrict__ lm,
               unsigned short* __restrict__ opart, float* __restrict__ mpart,
               float* __restrict__ lpart)
{
    const int qt = blockIdx.x, h = blockIdx.y;
    const int b = blockIdx.z >> 2, ch = blockIdx.z & 3;
    const int tid = threadIdx.x;
    const int w = tid >> 6, lane = tid & 63;
    const int c = lane & 15, g = lane >> 4;

    __shared__ unsigned short Ks[2][32 * 64];   // 32 keys x 64 d (granule-swizzled)
    __shared__ unsigned short Vs[2][64 * 32];   // 64 d x 32 keys (granule-swizzled)
    __shared__ float awS[2][512 * 4];           // 64q x 8 granules x 4 f32
    __shared__ int   mkS[2][512 * 4];
    __shared__ float lms[256];

    const size_t bh = (size_t)b * HN + h;
    const unsigned short* qbase  = qws  + (bh * NQ + (size_t)qt * 64) * DHEAD;
    const unsigned short* kbase  = kws  + (bh * NQ + (size_t)ch * 256) * DHEAD;
    const unsigned short* vtbase = vtws + bh * DHEAD * NQ + ch * 256;

    // aw/mask granule staging: thread covers granule pos=it*256+tid ->
    // q = pos>>3, kg_swz = pos&7, actual kg = kg_swz ^ (q&7). (q+32)&7 == q&7,
    // so kg is shared between it=0 and it=1.
    const int sq0 = tid >> 3;                 // q for it=0 (0..31)
    const int skg = (tid & 7) ^ (sq0 & 7);    // source granule index 0..7
    const float* awg0 = aw + (bh * NQ + (size_t)(qt * 64 + sq0)) * NQ + ch * 256 + skg * 4;
    const float* awg1 = aw + (bh * NQ + (size_t)(qt * 64 + sq0 + 32)) * NQ + ch * 256 + skg * 4;
    const int*   mkg0 = mask + (bh * NQ + (size_t)(qt * 64 + sq0)) * NQ + ch * 256 + skg * 4;
    const int*   mkg1 = mask + (bh * NQ + (size_t)(qt * 64 + sq0 + 32)) * NQ + ch * 256 + skg * 4;

    auto stage = [&](int kt, int bufi) {
        {   // K: 4KB, 1 gload/thread
            int r = tid >> 3, blk = tid & 7;
            int so = (blk ^ (r & 7)) << 3;
            gload16(kbase + (size_t)(kt * 32 + r) * DHEAD + so, &Ks[bufi][(w * 64) * 8]);
        }
        {   // V: 4KB, 1 gload/thread
            int r = tid >> 2, blk = tid & 3;
            int so = ((blk ^ ((tid >> 4) & 3)) << 3);
            gload16(vtbase + (size_t)r * NQ + kt * 32 + so, &Vs[bufi][(w * 64) * 8]);
        }
        // aw/mask: 8KB each, 2 gloads/thread
        gload16(awg0 + kt * 32, &awS[bufi][(w * 64) * 4]);
        gload16(awg1 + kt * 32, &awS[bufi][(256 + w * 64) * 4]);
        gload16(mkg0 + kt * 32, &mkS[bufi][(w * 64) * 4]);
        gload16(mkg1 + kt * 32, &mkS[bufi][(256 + w * 64) * 4]);
    };

    // Q fragments (q-row = w*16 + c) direct from global
    const int qrow = w * 16 + c;
    const bf16x8 qf0 = *(const bf16x8*)&qbase[qrow * DHEAD + g * 8];
    const bf16x8 qf1 = *(const bf16x8*)&qbase[qrow * DHEAD + 32 + g * 8];

    f32x4 O[4] = {{0,0,0,0},{0,0,0,0},{0,0,0,0},{0,0,0,0}};
    float mrun = -1e30f, lrun = 0.f;
    const int srcl = c + ((g & 1) << 5);   // c + 32*(g&1)
    const bool hiT = (g >> 1) != 0;
    const int vsw = (c >> 2);              // V read swizzle: chunk = g ^ (c>>2)
    // aw/mk read granule positions (conflict-optimal): pos = qrow*8 + (((nt<<2)|g) ^ (c&7))
    const int rp0 = qrow * 8 + ((g) ^ (c & 7));
    const int rp1 = qrow * 8 + ((4 | g) ^ (c & 7));

    lms[tid] = lm[((size_t)b * NQ + ch * 256 + tid) * HN + h];
    stage(0, 0);
    __syncthreads();   // lms written + tile 0 staged

    #pragma unroll
    for (int kt = 0; kt < 8; ++kt) {
        const int cur = kt & 1;
        if (kt < 7) stage(kt + 1, cur ^ 1);

        // aw/mask from LDS (staged one tile ago), lm from lms
        float4 aw4[2]; int4 mk4[2]; float4 lm4[2];
        aw4[0] = *(const float4*)&awS[cur][rp0 * 4];
        aw4[1] = *(const float4*)&awS[cur][rp1 * 4];
        mk4[0] = *(const int4*)&mkS[cur][rp0 * 4];
        mk4[1] = *(const int4*)&mkS[cur][rp1 * 4];
        lm4[0] = *(const float4*)&lms[kt * 32 + 4 * g];
        lm4[1] = *(const float4*)&lms[kt * 32 + 16 + 4 * g];

        // S^T = K Q^T  (rows=keys 32, cols=q 16)
        f32x4 s[2] = {{0,0,0,0},{0,0,0,0}};
        #pragma unroll
        for (int kk = 0; kk < 2; ++kk) {
            bf16x8 qf = kk ? qf1 : qf0;
            #pragma unroll
            for (int nt = 0; nt < 2; ++nt) {
                int krow = nt * 16 + c;
                bf16x8 kf = *(const bf16x8*)&Ks[cur][krow * 64 + ((((kk << 2) | g) ^ (c & 7)) << 3)];
                s[nt] = __builtin_amdgcn_mfma_f32_16x16x32_bf16(kf, qf, s[nt], 0, 0, 0);
            }
        }

        // scores + online softmax (per lane: one q=c, 8 keys)
        float p[2][4];
        float tmax = -INFINITY;
        #pragma unroll
        for (int nt = 0; nt < 2; ++nt) {
            const float* av = (const float*)&aw4[nt];
            const int*   mv = (const int*)&mk4[nt];
            const float* lv = (const float*)&lm4[nt];
            #pragma unroll
            for (int j = 0; j < 4; ++j) {
                float v = mv[j] ? -1e30f : fmaf(s[nt][j], 0.125f * av[j], lv[j]);
                p[nt][j] = v;
                tmax = fmaxf(tmax, v);
            }
        }
        tmax = fmaxf(tmax, __shfl_xor(tmax, 16));
        tmax = fmaxf(tmax, __shfl_xor(tmax, 32));

        float mn = fmaxf(mrun, tmax);
        float scal = __expf(mrun - mn);
        mrun = mn;
        float rs = 0.f;
        #pragma unroll
        for (int nt = 0; nt < 2; ++nt)
            #pragma unroll
            for (int j = 0; j < 4; ++j) {
                float e = __expf(p[nt][j] - mn);
                p[nt][j] = e;
                rs += e;
            }
        rs += __shfl_xor(rs, 16);
        rs += __shfl_xor(rs, 32);
        lrun = lrun * scal + rs;
        #pragma unroll
        for (int nd = 0; nd < 4; ++nd) O[nd] *= scal;

        // pack P to bf16 pairs: pk[nt][0]=(j0,j1), pk[nt][1]=(j2,j3)
        int pk[2][2];
        #pragma unroll
        for (int nt = 0; nt < 2; ++nt) {
            pk[nt][0] = (int)pack2(p[nt][0], p[nt][1]);
            pk[nt][1] = (int)pack2(p[nt][2], p[nt][3]);
        }

        // PV: O^T += V^T P^T ; B-frag (keys 8g..8g+7, q=c) via shfl
        {
            int xa0 = __shfl(pk[0][0], srcl),      xb0 = __shfl(pk[1][0], srcl);
            int xa1 = __shfl(pk[0][1], srcl),      xb1 = __shfl(pk[1][1], srcl);
            int xa2 = __shfl(pk[0][0], srcl + 16), xb2 = __shfl(pk[1][0], srcl + 16);
            int xa3 = __shfl(pk[0][1], srcl + 16), xb3 = __shfl(pk[1][1], srcl + 16);
            int4 bi;
            bi.x = hiT ? xb0 : xa0;
            bi.y = hiT ? xb1 : xa1;
            bi.z = hiT ? xb2 : xa2;
            bi.w = hiT ? xb3 : xa3;
            bf16x8 pa = __builtin_bit_cast(bf16x8, bi);
            #pragma unroll
            for (int nd = 0; nd < 4; ++nd) {
                int vrow = nd * 16 + c;
                bf16x8 vf = *(const bf16x8*)&Vs[cur][vrow * 32 + ((g ^ vsw) << 3)];
                O[nd] = __builtin_amdgcn_mfma_f32_16x16x32_bf16(vf, pa, O[nd], 0, 0, 0);
            }
        }
        if (kt < 7) __syncthreads();   // reads of cur done; staged tile visible
    }

    // store un-normalized partials as fp16 (d = nd*16 + 4g + j)
    const size_t prow = ((size_t)(ch * NB + b) * HN + h) * NQ + qt * 64 + qrow;
    #pragma unroll
    for (int nd = 0; nd < 4; ++nd) {
        ushort4 u;
        u.x = f2h(O[nd][0]); u.y = f2h(O[nd][1]);
        u.z = f2h(O[nd][2]); u.w = f2h(O[nd][3]);
        *(ushort4*)&opart[prow * 64 + nd * 16 + 4 * g] = u;
    }
    if (g == 0) {
        mpart[prow] = mrun;
        lpart[prow] = lrun;
    }
}

// ---------- combine partials ----------
__global__ __launch_bounds__(256)
void attn_combine(const unsigned short* __restrict__ opart, const float* __restrict__ mpart,
                  const float* __restrict__ lpart, unsigned short* __restrict__ out)
{
    const int qt = blockIdx.x, h = blockIdx.y, b = blockIdx.z;
    const int tid = threadIdx.x;
    const int q = qt * 64 + (tid >> 2);
    const int d0 = (tid & 3) * 16;
    const size_t row = ((size_t)b * HN + h) * NQ + q;

    float mv[NCH], lv[NCH];
    float M = -INFINITY;
    #pragma unroll
    for (int ci = 0; ci < NCH; ++ci) {
        mv[ci] = mpart[ci * CHROWS + row];
        lv[ci] = lpart[ci * CHROWS + row];
        M = fmaxf(M, mv[ci]);
    }
    float L = 0.f;
    float wc[NCH];
    #pragma unroll
    for (int ci = 0; ci < NCH; ++ci) {
        wc[ci] = __expf(mv[ci] - M);
        L += lv[ci] * wc[ci];
    }
    const float inv = 1.f / L;

    float o[16] = {};
    #pragma unroll
    for (int ci = 0; ci < NCH; ++ci) {
        const unsigned short* src = opart + (ci * CHROWS + row) * 64 + d0;
        #pragma unroll
        for (int i = 0; i < 4; ++i) {
            ushort4 u = *(const ushort4*)&src[i * 4];
            o[i * 4 + 0] += wc[ci] * __half2float(__ushort_as_half(u.x));
            o[i * 4 + 1] += wc[ci] * __half2float(__ushort_as_half(u.y));
            o[i * 4 + 2] += wc[ci] * __half2float(__ushort_as_half(u.z));
            o[i * 4 + 3] += wc[ci] * __half2float(__ushort_as_half(u.w));
        }
    }
    const size_t ob = ((size_t)b * NQ + q) * DMODEL + h * DHEAD + d0;
    #pragma unroll
    for (int i = 0; i < 4; ++i) {
        ushort4 u;
        u.x = f2bf(o[i * 4 + 0] * inv);
        u.y = f2bf(o[i * 4 + 1] * inv);
        u.z = f2bf(o[i * 4 + 2] * inv);
        u.w = f2bf(o[i * 4 + 3] * inv);
        *(ushort4*)&out[ob + i * 4] = u;
    }
}

extern "C" void kernel_launch(void* const* d_in, const int* in_sizes, int n_in,
                              void* d_out, int out_size, void* d_ws, size_t ws_size,
                              hipStream_t stream)
{
    const float* queries = (const float*)d_in[0];
    const float* keys    = (const float*)d_in[1];
    const float* values  = (const float*)d_in[2];
    const float* lossmap = (const float*)d_in[3];
    const int*   mask    = (const int*)d_in[4];
    const float* aw      = (const float*)d_in[5];
    const float* Wq = (const float*)d_in[6];
    const float* bq = (const float*)d_in[7];
    const float* Wk = (const float*)d_in[8];
    const float* bk = (const float*)d_in[9];
    const float* Wv = (const float*)d_in[10];
    const float* bv = (const float*)d_in[11];
    const float* Wo = (const float*)d_in[12];
    const float* bo = (const float*)d_in[13];

    unsigned short* p = (unsigned short*)d_ws;
    unsigned short* qbf  = p; p += PER;
    unsigned short* kbf  = p; p += PER;
    unsigned short* vbf  = p; p += PER;
    unsigned short* qws  = p; p += PER;
    unsigned short* kws  = p; p += PER;
    unsigned short* vtws = p; p += PER;
    unsigned short* aobf = p; p += PER;
    unsigned short* wqt  = p; p += WN;
    unsigned short* wkt  = p; p += WN;
    unsigned short* wvt  = p; p += WN;
    unsigned short* wot  = p; p += WN;
    unsigned short* opart = p; p += (size_t)NCH * CHROWS * 64;   // 25.2 MB fp16
    float* fp = (float*)p;
    float* mpart = fp; fp += (size_t)NCH * CHROWS;
    float* lpart = fp; fp += (size_t)NCH * CHROWS;

    const int M = MROWS;  // 4096
    cvt3<<<dim3((unsigned)(PER / 1024), 1, 3), 256, 0, stream>>>(queries, keys, values, qbf, kbf, vbf);
    wtrans<<<dim3(12, 12, 4), 256, 0, stream>>>(Wq, Wk, Wv, Wo, wqt, wkt, wvt, wot);
    qkv_gemm<<<dim3(DMODEL / 128, M / 128, 3), 256, 0, stream>>>(
        qbf, kbf, vbf, wqt, wkt, wvt, bq, bk, bv, qws, kws, vtws);
    attn_part<<<dim3(NQ / 64, HN, NB * NCH), 256, 0, stream>>>(
        qws, kws, vtws, aw, mask, lossmap, opart, mpart, lpart);
    attn_combine<<<dim3(NQ / 64, HN, NB), 256, 0, stream>>>(opart, mpart, lpart, aobf);
    o_gemm<<<dim3(DMODEL / 128, M / 128), 256, 0, stream>>>(aobf, wot, bo, (float*)d_out);
}